// Round 10
// baseline (17294.197 us; speedup 1.0000x reference)
//
#include <hip/hip_runtime.h>
#include <hip/hip_bf16.h>

#define EMBED   1024
#define HIDDEN  2048
#define G4      8192   // 4*HIDDEN
#define LENGTH  4096

typedef unsigned int   u32;
typedef unsigned short u16;
typedef __attribute__((ext_vector_type(4))) float f32x4;
typedef __attribute__((ext_vector_type(8))) short short8;
typedef __attribute__((ext_vector_type(4))) u32   u32x4;

__device__ __forceinline__ u16 f2bf(float x){
  __hip_bfloat16 h = __float2bfloat16(x);   // RNE
  return __builtin_bit_cast(u16, h);
}
__device__ __forceinline__ float bf2f(u16 b){
  return __uint_as_float(((u32)b) << 16);
}

#if __has_builtin(__builtin_amdgcn_fdot2_f32_bf16)
typedef __attribute__((ext_vector_type(2))) __bf16 bf16x2;
__device__ __forceinline__ float dot2acc(u32 a, u32 b, float c){
  return __builtin_amdgcn_fdot2_f32_bf16(__builtin_bit_cast(bf16x2, a),
                                         __builtin_bit_cast(bf16x2, b), c, false);
}
#else
__device__ __forceinline__ float dot2acc(u32 a, u32 b, float c){
  float r = c;
  r += __uint_as_float(a << 16)          * __uint_as_float(b << 16);
  r += __uint_as_float(a & 0xffff0000u)  * __uint_as_float(b & 0xffff0000u);
  return r;
}
#endif

__device__ __forceinline__ float fsig(float x){ return 1.f/(1.f + __expf(-x)); }
__device__ __forceinline__ float ftanh_(float x){ return 1.f - 2.f/(1.f + __expf(2.f*x)); }

// DPP wave64 sum: VALU-only butterfly (no LDS-pipe traffic). Total in lane 63.
#define DPP_ADD(x, CTRL) \
  x += __int_as_float(__builtin_amdgcn_update_dpp(0, __float_as_int(x), CTRL, 0xF, 0xF, true))
#define DPP_REDUCE(x) { DPP_ADD(x, 0xB1); DPP_ADD(x, 0x4E); DPP_ADD(x, 0x124); \
                        DPP_ADD(x, 0x128); DPP_ADD(x, 0x142); DPP_ADD(x, 0x143); }

// ---------------- fp32 -> bf16 conversion (vectorized) ----------------
__global__ void conv_bf16(const float* __restrict__ src, u16* __restrict__ dst, int n4){
  int i = blockIdx.x * blockDim.x + threadIdx.x;
  if (i < n4){
    float4 v = reinterpret_cast<const float4*>(src)[i];
    ushort4 o;
    o.x = f2bf(v.x); o.y = f2bf(v.y); o.z = f2bf(v.z); o.w = f2bf(v.w);
    reinterpret_cast<ushort4*>(dst)[i] = o;
  }
}

// ---------------- x_proj GEMM: out[m][j][g] = sum_k A[m][k]*B[g*2048+j][k] + bias ----------------
__global__ __launch_bounds__(256) void gemm_xproj(
    const u16* __restrict__ A, const u16* __restrict__ B,
    const float* __restrict__ b_ih, const float* __restrict__ b_hh,
    u16* __restrict__ C)
{
  __shared__ __align__(16) u16 As[64][40];
  __shared__ __align__(16) u16 Bs[64][40];
  const int tid  = threadIdx.x;
  const int lane = tid & 63, wid = tid >> 6;
  const int wr = wid >> 1, wc = wid & 1;
  const int m0 = blockIdx.y * 64, n0 = blockIdx.x * 64;
  const int srow = tid >> 2, sseg = (tid & 3) * 8;

  f32x4 acc[2][2] = {};
  for (int k0 = 0; k0 < EMBED; k0 += 32){
    *(short8*)&As[srow][sseg] = *(const short8*)&A[(size_t)(m0 + srow) * EMBED + k0 + sseg];
    *(short8*)&Bs[srow][sseg] = *(const short8*)&B[(size_t)(n0 + srow) * EMBED + k0 + sseg];
    __syncthreads();
    const int rr = lane & 15, kg = (lane >> 4) * 8;
    #pragma unroll
    for (int mi = 0; mi < 2; ++mi){
      short8 a = *(const short8*)&As[wr*32 + mi*16 + rr][kg];
      #pragma unroll
      for (int ni = 0; ni < 2; ++ni){
        short8 b = *(const short8*)&Bs[wc*32 + ni*16 + rr][kg];
        acc[mi][ni] = __builtin_amdgcn_mfma_f32_16x16x32_bf16(a, b, acc[mi][ni], 0, 0, 0);
      }
    }
    __syncthreads();
  }
  const int rr = lane & 15, rg = (lane >> 4) * 4;
  #pragma unroll
  for (int ni = 0; ni < 2; ++ni){
    int n = n0 + wc*32 + ni*16 + rr;      // n = gate*2048 + j
    int g = n >> 11, j = n & 2047;
    float bias = b_ih[n] + b_hh[n];
    #pragma unroll
    for (int mi = 0; mi < 2; ++mi){
      #pragma unroll
      for (int r = 0; r < 4; ++r){
        int m = m0 + wr*32 + mi*16 + rg + r;
        C[(size_t)m * G4 + j*4 + g] = f2bf(acc[mi][ni][r] + bias);
      }
    }
  }
}

// ---------------- persistent LSTM scan (register-resident weights) ----------------
// 256 WGs x 512 threads, 1 WG/CU (grid-limited). Wave w of WG wg owns hidden
// unit j = wg*8 + w (gate rows g*2048+j). W_hh slice staged ONCE into 64 NAMED
// scalar u32 VGPRs per lane (packed bf16 pairs), pinned with asm "+v".
// amdgpu_waves_per_eu(2,2) lifts the allocator's default 8-waves/EU 64-VGPR
// budget to 256 -- R8 PROVED 64 pinned weight VGPRs stay live across the poll
// with zero spill under this attribute (VGPR=88, no FETCH bloat); R2/3/4
// failed ONLY because of that cap. Per-step weight traffic is now zero on
// every pipe: no L2 stream (R2: 64MB/step, ~1.7us serialized), no LDS burst
// (R6), no prefetch straddle (R7/R8). Step = poll || xp-load -> 4 ds_write_b16
// -> __syncthreads -> 4 ds_read_b128 -> 64 dot2 -> DPP -> gates -> publish.
// Column mapping (verified R2-R9, 0 bank conflicts): word q=r*4+i of gate g
// holds columns r*512 + lane*8 + 2i,2i+1; h_bf[r*512+i] = h[r*512+i].
// h broadcast: htag[2][2048] words (tag<<16 | bf16(h)), relaxed agent-scope
// atomics, double-buffered by parity; tag+data in one word -> no fences.
#define PK2(x,y) ((u32)f2bf(x) | ((u32)f2bf(y) << 16))

#define DECL16(g) u32 w##g##_0, w##g##_1, w##g##_2,  w##g##_3,  w##g##_4,  w##g##_5,  w##g##_6,  w##g##_7, \
                      w##g##_8, w##g##_9, w##g##_10, w##g##_11, w##g##_12, w##g##_13, w##g##_14, w##g##_15

#define STAGE_GATE(g) { \
  const float* row_ = Whh + (size_t)((g)*HIDDEN + jrow) * HIDDEN + lane*8; \
  float4 a_, b_; \
  a_ = *(const float4*)(row_ +    0); b_ = *(const float4*)(row_ +    4); \
  w##g##_0  = PK2(a_.x,a_.y); w##g##_1  = PK2(a_.z,a_.w); w##g##_2  = PK2(b_.x,b_.y); w##g##_3  = PK2(b_.z,b_.w); \
  a_ = *(const float4*)(row_ +  512); b_ = *(const float4*)(row_ +  516); \
  w##g##_4  = PK2(a_.x,a_.y); w##g##_5  = PK2(a_.z,a_.w); w##g##_6  = PK2(b_.x,b_.y); w##g##_7  = PK2(b_.z,b_.w); \
  a_ = *(const float4*)(row_ + 1024); b_ = *(const float4*)(row_ + 1028); \
  w##g##_8  = PK2(a_.x,a_.y); w##g##_9  = PK2(a_.z,a_.w); w##g##_10 = PK2(b_.x,b_.y); w##g##_11 = PK2(b_.z,b_.w); \
  a_ = *(const float4*)(row_ + 1536); b_ = *(const float4*)(row_ + 1540); \
  w##g##_12 = PK2(a_.x,a_.y); w##g##_13 = PK2(a_.z,a_.w); w##g##_14 = PK2(b_.x,b_.y); w##g##_15 = PK2(b_.z,b_.w); }

#define OPQ(x) asm volatile("" : "+v"(x))
#define OPQ16(g) { OPQ(w##g##_0); OPQ(w##g##_1); OPQ(w##g##_2);  OPQ(w##g##_3); \
                   OPQ(w##g##_4); OPQ(w##g##_5); OPQ(w##g##_6);  OPQ(w##g##_7); \
                   OPQ(w##g##_8); OPQ(w##g##_9); OPQ(w##g##_10); OPQ(w##g##_11); \
                   OPQ(w##g##_12);OPQ(w##g##_13);OPQ(w##g##_14); OPQ(w##g##_15); }

#define DOT_GATE(acc, g) { \
  acc = dot2acc(w##g##_0,  ha[0], acc); acc = dot2acc(w##g##_1,  ha[1], acc); \
  acc = dot2acc(w##g##_2,  ha[2], acc); acc = dot2acc(w##g##_3,  ha[3], acc); \
  acc = dot2acc(w##g##_4,  hb[0], acc); acc = dot2acc(w##g##_5,  hb[1], acc); \
  acc = dot2acc(w##g##_6,  hb[2], acc); acc = dot2acc(w##g##_7,  hb[3], acc); \
  acc = dot2acc(w##g##_8,  hc[0], acc); acc = dot2acc(w##g##_9,  hc[1], acc); \
  acc = dot2acc(w##g##_10, hc[2], acc); acc = dot2acc(w##g##_11, hc[3], acc); \
  acc = dot2acc(w##g##_12, hd[0], acc); acc = dot2acc(w##g##_13, hd[1], acc); \
  acc = dot2acc(w##g##_14, hd[2], acc); acc = dot2acc(w##g##_15, hd[3], acc); }

__global__ __attribute__((amdgpu_waves_per_eu(2, 2))) __launch_bounds__(512)
void lstm_scan(
    const float* __restrict__ Whh,   // [8192][2048] fp32
    const u16*  __restrict__ xp,     // [4096][2048][4] bf16 (packed by gemm)
    u32* htag)                       // [2][2048]
{
  __shared__ __align__(16) u16 h_bf[4 * 512];   // h_bf[r*512+i] = h[r*512+i]

  const int wg = blockIdx.x;
  const int tid = threadIdx.x;
  const int w = tid >> 6, lane = tid & 63;
  const int jrow = wg*8 + w;

  // ---- one-time weight staging: fp32 global -> 64 named VGPRs (bf16 pairs) ----
  DECL16(0); DECL16(1); DECL16(2); DECL16(3);
  STAGE_GATE(0); STAGE_GATE(1); STAGE_GATE(2); STAGE_GATE(3);
  OPQ16(0); OPQ16(1); OPQ16(2); OPQ16(3);

  float c_reg = 0.f;

  for (int t = 0; t < LENGTH; ++t){
    // xp load (vmem; result needed only at step end -> hides under the poll)
    ushort4 xv = {0,0,0,0};
    if (lane == 63) xv = *(const ushort4*)(xp + (size_t)t * G4 + jrow * 4);

    // ---- acquire step-t h (tag == t): double-buffered coalesced poll ----
    u32* src = htag + ((t & 1) << 11);
    const u32 tt = (u32)t << 16;
    u32 v0, v1, v2, v3;
    {
      u32 a0,a1,a2,a3, b0,b1,b2,b3;
      #define LOADSET(x0,x1,x2,x3) \
        x0 = __hip_atomic_load(&src[tid       ], __ATOMIC_RELAXED, __HIP_MEMORY_SCOPE_AGENT); \
        x1 = __hip_atomic_load(&src[tid +  512], __ATOMIC_RELAXED, __HIP_MEMORY_SCOPE_AGENT); \
        x2 = __hip_atomic_load(&src[tid + 1024], __ATOMIC_RELAXED, __HIP_MEMORY_SCOPE_AGENT); \
        x3 = __hip_atomic_load(&src[tid + 1536], __ATOMIC_RELAXED, __HIP_MEMORY_SCOPE_AGENT)
      #define CHK(x0,x1,x2,x3) \
        ((((x0 ^ tt) | (x1 ^ tt) | (x2 ^ tt) | (x3 ^ tt)) & 0xffff0000u) == 0u)
      LOADSET(a0,a1,a2,a3);
      for (;;){
        LOADSET(b0,b1,b2,b3);
        if (CHK(a0,a1,a2,a3)){ v0=a0; v1=a1; v2=a2; v3=a3; break; }
        LOADSET(a0,a1,a2,a3);
        if (CHK(b0,b1,b2,b3)){ v0=b0; v1=b1; v2=b2; v3=b3; break; }
      }
      #undef LOADSET
      #undef CHK
    }
    h_bf[0*512 + tid] = (u16)v0;
    h_bf[1*512 + tid] = (u16)v1;
    h_bf[2*512 + tid] = (u16)v2;
    h_bf[3*512 + tid] = (u16)v3;
    __syncthreads();

    // h fragments: chunk r covers h[r*512 + lane*8 .. +7] (conflict-free b128)
    u32x4 ha = *(const u32x4*)&h_bf[0*512 + lane*8];
    u32x4 hb = *(const u32x4*)&h_bf[1*512 + lane*8];
    u32x4 hc = *(const u32x4*)&h_bf[2*512 + lane*8];
    u32x4 hd = *(const u32x4*)&h_bf[3*512 + lane*8];

    float a0 = 0.f, a1 = 0.f, a2 = 0.f, a3 = 0.f;
    DOT_GATE(a0, 0); DOT_GATE(a1, 1); DOT_GATE(a2, 2); DOT_GATE(a3, 3);

    // VALU-only wave64 reduction; totals valid in lane 63
    DPP_REDUCE(a0); DPP_REDUCE(a1); DPP_REDUCE(a2); DPP_REDUCE(a3);

    if (lane == 63){
      float gi = fsig (a0 + bf2f(xv.x));
      float gf = fsig (a1 + bf2f(xv.y));
      float gg = ftanh_(a2 + bf2f(xv.z));
      float go = fsig (a3 + bf2f(xv.w));
      c_reg = gf * c_reg + gi * gg;
      float h = go * ftanh_(c_reg);
      u32 word = ((u32)(t + 1) << 16) | (u32)f2bf(h);
      __hip_atomic_store(&htag[(((t + 1) & 1) << 11) + jrow], word,
                         __ATOMIC_RELAXED, __HIP_MEMORY_SCOPE_AGENT);
    }
    // single barrier per step: poll success for t+1 implies every wave
    // published t+1, which happens only after it finished reading step-t h_bf.
  }
}

// ---------------- final head: sigmoid(h . W_fc + b_fc) ----------------
__global__ __launch_bounds__(256) void head_k(const u32* __restrict__ htag,
                                              const float* __restrict__ Wfc,
                                              const float* __restrict__ bfc,
                                              float* __restrict__ out){
  __shared__ float red[256];
  int tid = threadIdx.x;
  float s = 0.f;
  #pragma unroll
  for (int k = 0; k < 8; ++k){
    int j = tid * 8 + k;
    s += bf2f((u16)(htag[j] & 0xffffu)) * Wfc[j];   // tag 4096 lives in buffer 0
  }
  red[tid] = s;
  __syncthreads();
  for (int k = 128; k > 0; k >>= 1){
    if (tid < k) red[tid] += red[tid + k];
    __syncthreads();
  }
  if (tid == 0) out[0] = 1.f / (1.f + __expf(-(red[0] + bfc[0])));
}

// ---------------- launch ----------------
extern "C" void kernel_launch(void* const* d_in, const int* in_sizes, int n_in,
                              void* d_out, int out_size, void* d_ws, size_t ws_size,
                              hipStream_t stream){
  const float* x   = (const float*)d_in[0];   // [1,4096,1024]
  const float* Wih = (const float*)d_in[1];   // [8192,1024]
  const float* Whh = (const float*)d_in[2];   // [8192,2048]
  const float* bih = (const float*)d_in[3];   // [8192]
  const float* bhh = (const float*)d_in[4];   // [8192]
  const float* Wfc = (const float*)d_in[5];   // [1,2048]
  const float* bfc = (const float*)d_in[6];   // [1]
  float* out = (float*)d_out;

  char* ws = (char*)d_ws;
  u16* xp     = (u16*)(ws);                    // 4096*8192*2 = 67108864
  u16* x_bf   = (u16*)(ws + 67108864);         // 8388608
  u16* wih_bf = (u16*)(ws + 75497472);         // 16777216
  u32* htag   = (u32*)(ws + 92274688);         // 2*2048*4 = 16384

  hipMemsetAsync(htag, 0, 2 * HIDDEN * sizeof(u32), stream);
  conv_bf16<<<(EMBED*LENGTH/4 + 255)/256, 256, 0, stream>>>(x, x_bf, EMBED*LENGTH/4);
  conv_bf16<<<(G4*EMBED/4 + 255)/256, 256, 0, stream>>>(Wih, wih_bf, G4*EMBED/4);
  dim3 gg(G4/64, LENGTH/64);
  gemm_xproj<<<gg, 256, 0, stream>>>(x_bf, wih_bf, bih, bhh, xp);
  lstm_scan<<<256, 512, 0, stream>>>(Whh, xp, htag);
  head_k<<<1, 256, 0, stream>>>(htag, Wfc, bfc, out);
}